// Round 19
// baseline (51.961 us; speedup 1.0000x reference)
//
#include <hip/hip_runtime.h>
#include <math.h>

// DecoderGATLayer — 2 flat kernels. f32. S=192, B=2, E=512, H=2, D=256, BH=4.
// Dead inputs: ex_entity, ex_relation, Wxe, Wxr (reference deletes `we`).
// score[bh,t,s] = A[s&3][i] + B[t&3][s] + C[s&3][i] - C[s&3][j] + ba,
//   i = bh*48 + (t>>2), j = (t&3)*48 + (s>>2)
// q/k projections folded into tables via u = W^T wa_slice (verified r7).
// K1: proj (in-LDS transpose of pristine Wv/We) + Wo->WTO + tables (r18 body).
// K2: block=(b,tg,cg:2): softmax (both heads) + PV -> rows[4][512] -> ws
//     roundtrip (s_load + s_dcache_inv, r13-proven) -> GEMV over 256-col slice.

#define SS 192
// ws float offsets
#define WTO 262144     // [128 k4][512 c] float4-over-k
#define TO  524288     // 12*192 tables
#define VO  526592     // [384][256], row = s*2+b
#define EO  624896
#define ROWS 723200    // per-block rows: [192 blk][4 ti][512]
// end 1116416 floats = 4.3 MB

__device__ __forceinline__ float wave_reduce_add(float p) {
    #pragma unroll
    for (int off = 32; off >= 1; off >>= 1) p += __shfl_xor(p, off, 64);
    return p;
}

// ===== K1: blocks 0..191 proj (LDS-staged W transpose);
//           192..255 Wo transpose; 256..263 A/B tables; 264..267 C tables.
__global__ __launch_bounds__(1024) void k_projprep(
    const float* __restrict__ query, const float* __restrict__ entity,
    const float* __restrict__ Wq, const float* __restrict__ bq,
    const float* __restrict__ Wk, const float* __restrict__ bk,
    const float* __restrict__ Wv, const float* __restrict__ bv,
    const float* __restrict__ We, const float* __restrict__ be,
    const float* __restrict__ Wa, const float* __restrict__ Wo,
    float* __restrict__ ws)
{
    __shared__ __align__(16) float shb[8448];   // proj: WL f4[16][129] / part; tables: red
    __shared__ __align__(16) float uo[516];
    int blk = blockIdx.x;
    int tid = threadIdx.x;
    int wv   = __builtin_amdgcn_readfirstlane(tid >> 6);
    int lane = tid & 63;

    if (blk < 192) {
        // ---- v,e projections: (m:2, dh:2, rg:48) -> 8 rows x 128 cols.
        int m   = blk / 96;                    // 0: v(query), 1: e(entity)
        int rem = blk % 96;
        int dh  = rem / 48;
        int rg  = rem % 48;
        int r0  = rg * 8;
        int d0  = dh * 128;
        int q   = __builtin_amdgcn_readfirstlane(tid >> 7);   // k-split 0..7
        int dl  = tid & 127;
        const float4* Wsrc = (const float4*)(m ? We : Wv);    // [256][128] natural
        const float*  bias = m ? be : bv;
        const float*  A    = m ? entity : query;
        float*        dst  = ws + (m ? EO : VO);
        const float4* A4   = (const float4*)A;                // [384][128]
        float4* WL = (float4*)shb;                            // [16][129] f4, padded

        float acc[8];
        #pragma unroll
        for (int r = 0; r < 8; r++) acc[r] = 0.f;

        for (int c = 0; c < 8; c++) {          // 8 chunks x 16 k4
            #pragma unroll
            for (int j = 0; j < 2; j++) {
                int idx  = tid + j * 1024;     // 0..2047
                int dloc = idx >> 4;           // 0..127
                int k4l  = idx & 15;           // 0..15
                WL[k4l * 129 + dloc] =
                    Wsrc[(size_t)(d0 + dloc) * 128 + c * 16 + k4l];
            }
            __syncthreads();
            #pragma unroll
            for (int j = 0; j < 2; j++) {
                int k4l = q * 2 + j;
                float4 w = WL[k4l * 129 + dl];              // conflict-free
                int k4 = c * 16 + k4l;
                #pragma unroll
                for (int r = 0; r < 8; r++) {
                    float4 a = A4[(size_t)(r0 + r) * 128 + k4];  // uniform -> s_load
                    acc[r] += a.x * w.x + a.y * w.y + a.z * w.z + a.w * w.w;
                }
            }
            __syncthreads();
        }
        float* part = shb;                     // [8 q][8 r][128 dl]
        #pragma unroll
        for (int r = 0; r < 8; r++) part[q * 1024 + r * 128 + dl] = acc[r];
        __syncthreads();
        {
            int r = tid >> 7, d2 = tid & 127;  // 1024 outputs, 1 each
            float v = 0.f;
            #pragma unroll
            for (int k = 0; k < 8; k++) v += part[k * 1024 + r * 128 + d2];
            dst[(size_t)(r0 + r) * 256 + d0 + d2] = v + bias[d0 + d2];
        }
        return;
    }

    if (blk < 256) {
        // ---- Wo transpose: WTO4[k4*512 + c] = Wo4[c*128 + k4]
        int o  = (blk - 192) * 1024 + tid;     // 0..65535
        int c  = o >> 7;
        int k4 = o & 127;
        ((float4*)(ws + WTO))[k4 * 512 + c] = ((const float4*)Wo)[o];
        return;
    }

    if (blk < 264) {
        // ---- A/B tables via u = W^T wa_slice (r17/r18 body)
        float* red = shb;
        int tab = blk - 256;                   // 0..7
        int p   = (tab < 4) ? tab : tab - 4;
        int b   = p >> 1, h = p & 1;
        const float* wa   = Wa + ((tab < 4) ? 0 : 256);
        const float* W    = h ? We : ((tab < 4) ? Wq : Wk);
        const float* bias = h ? be : ((tab < 4) ? bq : bk);
        const float* x    = h ? entity : query;

        float u8[8];
        #pragma unroll
        for (int i = 0; i < 8; i++) u8[i] = 0.f;
        #pragma unroll 4
        for (int dd = 0; dd < 16; dd++) {
            int d = wv * 16 + dd;
            float wad = wa[d];                                  // wave-uniform
            const float4* Wr = (const float4*)(W + (size_t)d * 512);
            float4 w0 = Wr[lane * 2], w1 = Wr[lane * 2 + 1];    // coalesced
            u8[0] += wad * w0.x; u8[1] += wad * w0.y; u8[2] += wad * w0.z; u8[3] += wad * w0.w;
            u8[4] += wad * w1.x; u8[5] += wad * w1.y; u8[6] += wad * w1.z; u8[7] += wad * w1.w;
        }
        if (wv < 8) {
            #pragma unroll
            for (int i = 0; i < 8; i++) red[wv * 512 + lane * 8 + i] = u8[i];
        }
        __syncthreads();
        if (wv >= 8) {
            #pragma unroll
            for (int i = 0; i < 8; i++)
                atomicAdd(&red[(wv - 8) * 512 + lane * 8 + i], u8[i]);  // LDS atomic
        }
        __syncthreads();
        if (tid < 512) {
            float s = 0.f;
            #pragma unroll
            for (int w = 0; w < 8; w++) s += red[w * 512 + tid];
            uo[tid] = s;
        }
        __syncthreads();
        if (tid < 256) red[tid] = wa[tid] * bias[tid];
        __syncthreads();
        for (int o = 128; o >= 1; o >>= 1) {
            if (tid < o) red[tid] += red[tid + o];
            __syncthreads();
        }
        float off = red[0];

        const float4* u4 = (const float4*)uo;
        float4 ua = u4[lane * 2], ub = u4[lane * 2 + 1];
        for (int rr = 0; rr < 12; rr++) {
            int r = wv * 12 + rr;
            const float4* xr = (const float4*)(x + (size_t)(r * 2 + b) * 512);
            float4 a0 = xr[lane * 2], a1 = xr[lane * 2 + 1];
            float pp = a0.x*ua.x + a0.y*ua.y + a0.z*ua.z + a0.w*ua.w
                     + a1.x*ub.x + a1.y*ub.y + a1.z*ub.z + a1.w*ub.w;
            pp = wave_reduce_add(pp);
            if (lane == 0) ws[TO + tab * SS + r] = pp + off;
        }
        return;
    }

    // ---- C tables (verified body)
    {
        int m = blk - 264;                     // 0..3
        float4 wa4 = ((const float4*)(Wa + 512))[lane];
        for (int rr = 0; rr < 12; rr++) {
            int i = wv * 12 + rr;
            const float4* er = (const float4*)(entity
                + (size_t)(i * 2 + (m >> 1)) * 512 + (m & 1) * 256);
            float4 e4 = er[lane];
            float pp = e4.x*wa4.x + e4.y*wa4.y + e4.z*wa4.z + e4.w*wa4.w;
            pp = wave_reduce_add(pp);
            if (lane == 0) ws[TO + (8 + m) * SS + i] = pp;
        }
    }
}

// ===== K2: attn + out fused. 192 blocks = (b:2, tg:48, cg:2) x 1024 thr.
__global__ __launch_bounds__(1024) void k_attnout(
    const float* __restrict__ ba_p, const float* __restrict__ bo,
    float* __restrict__ ws, float* __restrict__ out)
{
    __shared__ __align__(16) float spT[SS * 8];     // [s][h*4+ti]  6 KB
    __shared__ __align__(16) float pu[8192];        // 32 KB multi-use
    int blk = blockIdx.x;
    int b   = blk / 96;
    int rem = blk % 96;
    int tg  = rem >> 1;                    // t = tg*4 + ti
    int cg  = rem & 1;
    int tid  = threadIdx.x;
    int wvi  = __builtin_amdgcn_readfirstlane(tid >> 6);
    int lane = tid & 63;
    const float* T = ws + TO;
    float ba = ba_p[0];

    // --- softmax: waves 0..7 own (h = wvi>>2, ti = wvi&3)   [r13/r18 body]
    if (wvi < 8) {
        int h = wvi >> 2, ti = wvi & 3;
        int bh = 2 * b + h;
        int i_idx = bh * 48 + tg;
        float sc[3]; float mx = -1e30f;
        #pragma unroll
        for (int i = 0; i < 3; i++) {
            int s_ = lane + 64 * i;
            int m  = s_ & 3;
            int j  = ti * 48 + (s_ >> 2);
            float xv = T[m * SS + i_idx] + T[(4 + ti) * SS + s_]
                     + T[(8 + m) * SS + i_idx] - T[(8 + m) * SS + j] + ba;
            xv = (xv >= 0.f) ? xv : 0.01f * xv;      // leaky_relu
            sc[i] = xv; mx = fmaxf(mx, xv);
        }
        #pragma unroll
        for (int o = 32; o >= 1; o >>= 1) mx = fmaxf(mx, __shfl_xor(mx, o, 64));
        float sum = 0.f;
        #pragma unroll
        for (int i = 0; i < 3; i++) { sc[i] = __expf(sc[i] - mx); sum += sc[i]; }
        sum = wave_reduce_add(sum);
        float inv = 1.f / sum;
        #pragma unroll
        for (int i = 0; i < 3; i++)
            spT[(lane + 64 * i) * 8 + h * 4 + ti] = sc[i] * inv;
    }
    __syncthreads();

    // --- PV: thread (h = tid>>9, sq = (tid>>7)&3, d2 = tid&127), float2 (r13 body)
    {
        int h  = __builtin_amdgcn_readfirstlane(tid >> 9);
        int sq = __builtin_amdgcn_readfirstlane((tid >> 7) & 3);
        int d2 = tid & 127;
        const float2* src2 = (const float2*)(ws + (h ? EO : VO));   // [384][128]
        const float4* spT4 = (const float4*)spT;
        float2 acc2[4];
        #pragma unroll
        for (int ti = 0; ti < 4; ti++) acc2[ti] = make_float2(0.f, 0.f);
        int s0 = sq * 48;
        #pragma unroll 8
        for (int s2 = 0; s2 < 48; s2++) {
            int s = s0 + s2;
            float4 p4 = spT4[s * 2 + h];          // one b128 broadcast: 4 ti weights
            float2 v  = src2[(size_t)(s * 2 + b) * 128 + d2];
            acc2[0].x += p4.x * v.x; acc2[0].y += p4.x * v.y;
            acc2[1].x += p4.y * v.x; acc2[1].y += p4.y * v.y;
            acc2[2].x += p4.z * v.x; acc2[2].y += p4.z * v.y;
            acc2[3].x += p4.w * v.x; acc2[3].y += p4.w * v.y;
        }
        float2* pf2 = (float2*)pu;                // [(h*4+sq)*4+ti][128]
        #pragma unroll
        for (int ti = 0; ti < 4; ti++)
            pf2[((h * 4 + sq) * 4 + ti) * 128 + d2] = acc2[ti];
    }
    __syncthreads();

    // --- reduce partials -> rows in GLOBAL ws for s_load GEMV reads (r13 body)
    {
        const float* partf = pu;                  // [(h*4+sq)*4+ti][256]
        int ti = tid >> 8, dd = tid & 255;
        float r0 = 0.f, r1 = 0.f;
        #pragma unroll
        for (int sq = 0; sq < 4; sq++) {
            r0 += partf[((0 + sq) * 4 + ti) * 256 + dd];
            r1 += partf[((4 + sq) * 4 + ti) * 256 + dd];
        }
        float* wsrows = ws + ROWS + blk * 2048;
        wsrows[ti * 512 + dd]       = r0;
        wsrows[ti * 512 + 256 + dd] = r1;
    }
    __syncthreads();                              // drains vmcnt before barrier
    asm volatile("s_dcache_inv" ::: "memory");    // r13-proven replay-staleness guard

    // --- out GEMV over 256-col slice: thread (kc = tid>>8 [4], cl = tid&255)
    {
        int kc = __builtin_amdgcn_readfirstlane(tid >> 8);
        int cl = tid & 255;
        int c0 = cg * 256;
        const float4* rows4 = (const float4*)(ws + ROWS + blk * 2048);  // [4][128]
        const float4* WT    = (const float4*)(ws + WTO);                // [128][512]
        float acc[4];
        #pragma unroll
        for (int r = 0; r < 4; r++) acc[r] = 0.f;
        int k4b = kc * 32;
        #pragma unroll 8
        for (int i = 0; i < 32; i++) {
            int k4 = k4b + i;
            float4 w = WT[(size_t)k4 * 512 + c0 + cl];    // coalesced (4KB/wave pair)
            #pragma unroll
            for (int r = 0; r < 4; r++) {
                float4 a = rows4[r * 128 + k4];   // uniform -> s_load (post-inv)
                acc[r] += a.x * w.x + a.y * w.y + a.z * w.z + a.w * w.w;
            }
        }
        #pragma unroll
        for (int r = 0; r < 4; r++) pu[kc * 1024 + r * 256 + cl] = acc[r];
    }
    __syncthreads();
    // --- final reduce + store (1024 outputs, 1 per thread, coalesced)
    {
        int r = tid >> 8, cl = tid & 255;
        int c = cg * 256 + cl;
        float v = pu[r * 256 + cl] + pu[1024 + r * 256 + cl]
                + pu[2048 + r * 256 + cl] + pu[3072 + r * 256 + cl];
        int t = tg * 4 + r;
        out[(size_t)(2 * t + b) * 512 + c] = v + bo[c];
    }
}

extern "C" void kernel_launch(void* const* d_in, const int* in_sizes, int n_in,
                              void* d_out, int out_size, void* d_ws, size_t ws_size,
                              hipStream_t stream) {
    const float* query  = (const float*)d_in[0];
    const float* entity = (const float*)d_in[1];
    // d_in[2] ex_entity, d_in[3] ex_relation: dead
    const float* Wq = (const float*)d_in[4];  const float* bq = (const float*)d_in[5];
    const float* Wk = (const float*)d_in[6];  const float* bk = (const float*)d_in[7];
    const float* Wv = (const float*)d_in[8];  const float* bv = (const float*)d_in[9];
    const float* We = (const float*)d_in[10]; const float* be = (const float*)d_in[11];
    // d_in[12..15] dead
    const float* Wa = (const float*)d_in[16]; const float* ba = (const float*)d_in[17];
    const float* Wo = (const float*)d_in[18]; const float* bo = (const float*)d_in[19];
    float* ws  = (float*)d_ws;
    float* out = (float*)d_out;

    hipLaunchKernelGGL(k_projprep, dim3(268), dim3(1024), 0, stream,
                       query, entity, Wq, bq, Wk, bk, Wv, bv, We, be, Wa, Wo, ws);
    hipLaunchKernelGGL(k_attnout, dim3(192), dim3(1024), 0, stream,
                       ba, bo, ws, out);
}

// Round 20
// 40.033 us; speedup vs baseline: 1.2980x; 1.2980x over previous
//
#include <hip/hip_runtime.h>
#include <math.h>

// DecoderGATLayer — 3 flat kernels (r18 champion, reverted from r19). f32.
// S=192, B=2, E=512, H=2, D=256, BH=4.
// Dead inputs: ex_entity, ex_relation, Wxe, Wxr (reference deletes `we`).
// score[bh,t,s] = A[s&3][i] + B[t&3][s] + C[s&3][i] - C[s&3][j] + ba,
//   i = bh*48 + (t>>2), j = (t&3)*48 + (s>>2)
// q/k projections folded into tables via u = W^T wa_slice (verified r7).
// K1: proj (in-LDS transpose of pristine Wv/We slices; no k_prep dependency)
//     + Wo->WTO transpose (consumed 2 boundaries later by K3) + tables.
// K2: attn (r16 body).  K3: out fc (r16 body, reads WTO).
// Structure note: proj->attn and attn->out are all-to-all dependencies; every
// fused alternative measured worse (r10,r11,r13,r14,r19). 3 flat kernels is
// the measured optimum; remaining cost is dispatch/drain, not HW resources.

#define SS 192
// ws float offsets
#define WTO 262144     // [128 k4][512 c] float4-over-k
#define TO  524288     // 12*192 tables
#define VO  526592     // [384][256], row = s*2+b
#define EO  624896
#define OO  723200     // attn rows [384][512], row = 2t+b, col = h*256+d
// end 919808 floats = 3.5 MB

__device__ __forceinline__ float wave_reduce_add(float p) {
    #pragma unroll
    for (int off = 32; off >= 1; off >>= 1) p += __shfl_xor(p, off, 64);
    return p;
}

// ===== K1: blocks 0..191 proj (LDS-staged W transpose);
//           192..255 Wo transpose; 256..263 A/B tables; 264..267 C tables.
__global__ __launch_bounds__(1024) void k_projprep(
    const float* __restrict__ query, const float* __restrict__ entity,
    const float* __restrict__ Wq, const float* __restrict__ bq,
    const float* __restrict__ Wk, const float* __restrict__ bk,
    const float* __restrict__ Wv, const float* __restrict__ bv,
    const float* __restrict__ We, const float* __restrict__ be,
    const float* __restrict__ Wa, const float* __restrict__ Wo,
    float* __restrict__ ws)
{
    __shared__ __align__(16) float shb[8448];   // proj: WL f4[16][129] / part; tables: red
    __shared__ __align__(16) float uo[516];
    int blk = blockIdx.x;
    int tid = threadIdx.x;
    int wv   = __builtin_amdgcn_readfirstlane(tid >> 6);
    int lane = tid & 63;

    if (blk < 192) {
        // ---- v,e projections: (m:2, dh:2, rg:48) -> 8 rows x 128 cols.
        // Weight slice W[d0..+127][:] read PRISTINE + coalesced, transposed via LDS.
        int m   = blk / 96;                    // 0: v(query), 1: e(entity)
        int rem = blk % 96;
        int dh  = rem / 48;
        int rg  = rem % 48;
        int r0  = rg * 8;
        int d0  = dh * 128;
        int q   = __builtin_amdgcn_readfirstlane(tid >> 7);   // k-split 0..7
        int dl  = tid & 127;
        const float4* Wsrc = (const float4*)(m ? We : Wv);    // [256][128] natural
        const float*  bias = m ? be : bv;
        const float*  A    = m ? entity : query;
        float*        dst  = ws + (m ? EO : VO);
        const float4* A4   = (const float4*)A;                // [384][128]
        float4* WL = (float4*)shb;                            // [16][129] f4, padded

        float acc[8];
        #pragma unroll
        for (int r = 0; r < 8; r++) acc[r] = 0.f;

        for (int c = 0; c < 8; c++) {          // 8 chunks x 16 k4
            // stage: 2048 f4, 2 per thread, coalesced rows of Wsrc
            #pragma unroll
            for (int j = 0; j < 2; j++) {
                int idx  = tid + j * 1024;     // 0..2047
                int dloc = idx >> 4;           // 0..127
                int k4l  = idx & 15;           // 0..15
                WL[k4l * 129 + dloc] =
                    Wsrc[(size_t)(d0 + dloc) * 128 + c * 16 + k4l];
            }
            __syncthreads();
            #pragma unroll
            for (int j = 0; j < 2; j++) {
                int k4l = q * 2 + j;
                float4 w = WL[k4l * 129 + dl];              // conflict-free
                int k4 = c * 16 + k4l;
                #pragma unroll
                for (int r = 0; r < 8; r++) {
                    float4 a = A4[(size_t)(r0 + r) * 128 + k4];  // uniform -> s_load
                    acc[r] += a.x * w.x + a.y * w.y + a.z * w.z + a.w * w.w;
                }
            }
            __syncthreads();
        }
        // q-reduce via LDS (aliases WL, reads done)
        float* part = shb;                     // [8 q][8 r][128 dl]
        #pragma unroll
        for (int r = 0; r < 8; r++) part[q * 1024 + r * 128 + dl] = acc[r];
        __syncthreads();
        {
            int r = tid >> 7, d2 = tid & 127;  // 1024 outputs, 1 each
            float v = 0.f;
            #pragma unroll
            for (int k = 0; k < 8; k++) v += part[k * 1024 + r * 128 + d2];
            dst[(size_t)(r0 + r) * 256 + d0 + d2] = v + bias[d0 + d2];
        }
        return;
    }

    if (blk < 256) {
        // ---- Wo transpose: WTO4[k4*512 + c] = Wo4[c*128 + k4]
        int o  = (blk - 192) * 1024 + tid;     // 0..65535
        int c  = o >> 7;
        int k4 = o & 127;
        ((float4*)(ws + WTO))[k4 * 512 + c] = ((const float4*)Wo)[o];
        return;
    }

    if (blk < 264) {
        // ---- A/B tables via u = W^T wa_slice (r17 body)
        float* red = shb;
        int tab = blk - 256;                   // 0..7
        int p   = (tab < 4) ? tab : tab - 4;
        int b   = p >> 1, h = p & 1;
        const float* wa   = Wa + ((tab < 4) ? 0 : 256);
        const float* W    = h ? We : ((tab < 4) ? Wq : Wk);
        const float* bias = h ? be : ((tab < 4) ? bq : bk);
        const float* x    = h ? entity : query;

        float u8[8];
        #pragma unroll
        for (int i = 0; i < 8; i++) u8[i] = 0.f;
        #pragma unroll 4
        for (int dd = 0; dd < 16; dd++) {
            int d = wv * 16 + dd;
            float wad = wa[d];                                  // wave-uniform
            const float4* Wr = (const float4*)(W + (size_t)d * 512);
            float4 w0 = Wr[lane * 2], w1 = Wr[lane * 2 + 1];    // coalesced
            u8[0] += wad * w0.x; u8[1] += wad * w0.y; u8[2] += wad * w0.z; u8[3] += wad * w0.w;
            u8[4] += wad * w1.x; u8[5] += wad * w1.y; u8[6] += wad * w1.z; u8[7] += wad * w1.w;
        }
        if (wv < 8) {
            #pragma unroll
            for (int i = 0; i < 8; i++) red[wv * 512 + lane * 8 + i] = u8[i];
        }
        __syncthreads();
        if (wv >= 8) {
            #pragma unroll
            for (int i = 0; i < 8; i++)
                atomicAdd(&red[(wv - 8) * 512 + lane * 8 + i], u8[i]);  // LDS atomic
        }
        __syncthreads();
        if (tid < 512) {
            float s = 0.f;
            #pragma unroll
            for (int w = 0; w < 8; w++) s += red[w * 512 + tid];
            uo[tid] = s;
        }
        __syncthreads();
        if (tid < 256) red[tid] = wa[tid] * bias[tid];
        __syncthreads();
        for (int o = 128; o >= 1; o >>= 1) {
            if (tid < o) red[tid] += red[tid + o];
            __syncthreads();
        }
        float off = red[0];

        const float4* u4 = (const float4*)uo;
        float4 ua = u4[lane * 2], ub = u4[lane * 2 + 1];
        for (int rr = 0; rr < 12; rr++) {
            int r = wv * 12 + rr;
            const float4* xr = (const float4*)(x + (size_t)(r * 2 + b) * 512);
            float4 a0 = xr[lane * 2], a1 = xr[lane * 2 + 1];
            float pp = a0.x*ua.x + a0.y*ua.y + a0.z*ua.z + a0.w*ua.w
                     + a1.x*ub.x + a1.y*ub.y + a1.z*ub.z + a1.w*ub.w;
            pp = wave_reduce_add(pp);
            if (lane == 0) ws[TO + tab * SS + r] = pp + off;
        }
        return;
    }

    // ---- C tables (verified body)
    {
        int m = blk - 264;                     // 0..3
        float4 wa4 = ((const float4*)(Wa + 512))[lane];
        for (int rr = 0; rr < 12; rr++) {
            int i = wv * 12 + rr;
            const float4* er = (const float4*)(entity
                + (size_t)(i * 2 + (m >> 1)) * 512 + (m & 1) * 256);
            float4 e4 = er[lane];
            float pp = e4.x*wa4.x + e4.y*wa4.y + e4.z*wa4.z + e4.w*wa4.w;
            pp = wave_reduce_add(pp);
            if (lane == 0) ws[TO + (8 + m) * SS + i] = pp;
        }
    }
}

// ===== K2: attention. 384 blocks = (bh:4, tg:48, dhf:2). (r16 body verbatim)
__global__ __launch_bounds__(1024) void k_attn(
    const float* __restrict__ ba_p, float* __restrict__ ws)
{
    __shared__ __align__(16) float pl[4096];       // [8 sq][4 ti][128] 16 KB
    __shared__ __align__(16) float sp4[768];
    int blk = blockIdx.x;
    int bh  = blk & 3;
    int rem2 = blk >> 2;
    int tg  = rem2 % 48;                   // t = tg*4 + ti
    int dhf = rem2 / 48;                   // 0..1
    int b = bh >> 1, h = bh & 1;
    const float* T = ws + TO;
    float ba = ba_p[0];
    int tid  = threadIdx.x;
    int wv   = __builtin_amdgcn_readfirstlane(tid >> 6);
    int lane = tid & 63;

    if (wv < 4) {
        int ti = wv;
        int i_idx = bh * 48 + tg;
        float sc[3]; float mx = -1e30f;
        #pragma unroll
        for (int i = 0; i < 3; i++) {
            int s_ = lane + 64 * i;
            int m  = s_ & 3;
            int j  = ti * 48 + (s_ >> 2);
            float xv = T[m * SS + i_idx] + T[(4 + ti) * SS + s_]
                     + T[(8 + m) * SS + i_idx] - T[(8 + m) * SS + j] + ba;
            xv = (xv >= 0.f) ? xv : 0.01f * xv;      // leaky_relu
            sc[i] = xv; mx = fmaxf(mx, xv);
        }
        #pragma unroll
        for (int o = 32; o >= 1; o >>= 1) mx = fmaxf(mx, __shfl_xor(mx, o, 64));
        float sum = 0.f;
        #pragma unroll
        for (int i = 0; i < 3; i++) { sc[i] = __expf(sc[i] - mx); sum += sc[i]; }
        sum = wave_reduce_add(sum);
        float inv = 1.f / sum;
        #pragma unroll
        for (int i = 0; i < 3; i++) sp4[ti * SS + lane + 64 * i] = sc[i] * inv;
    }
    __syncthreads();

    int sq = __builtin_amdgcn_readfirstlane(tid >> 7);
    int dl = tid & 127;
    int dd = dhf * 128 + dl;
    const float* src = ws + (h ? EO : VO) + b * 256 + dd;
    float a[4] = {0.f, 0.f, 0.f, 0.f};
    int s0 = sq * 24;
    #pragma unroll 8
    for (int s2 = 0; s2 < 24; s2++) {
        int s = s0 + s2;
        float xv = src[(size_t)s * 512];
        #pragma unroll
        for (int ti = 0; ti < 4; ti++) a[ti] += sp4[ti * SS + s] * xv;
    }
    #pragma unroll
    for (int ti = 0; ti < 4; ti++) pl[sq * 512 + ti * 128 + dl] = a[ti];
    __syncthreads();
    if (tid < 512) {
        int ti = tid >> 7, d2 = tid & 127;
        float v = 0.f;
        #pragma unroll
        for (int k = 0; k < 8; k++) v += pl[k * 512 + ti * 128 + d2];
        int t = tg * 4 + ti;
        ws[OO + (size_t)(2 * t + b) * 512 + h * 256 + dhf * 128 + d2] = v;
    }
}

// ===== K3: output fc. 384 blocks = (rg:96, cg:4). (r16 body verbatim)
__global__ __launch_bounds__(1024) void k_out(
    const float* __restrict__ bo, const float* __restrict__ ws,
    float* __restrict__ out)
{
    __shared__ float pl[4096];                 // [8 kc][4 r][128 cl] 16 KB
    int blk = blockIdx.x;
    int rg  = blk >> 2;                        // 0..95
    int cg  = blk & 3;
    int r0  = rg * 4;
    int c0  = cg * 128;
    int tid = threadIdx.x;
    int kc  = __builtin_amdgcn_readfirstlane(tid >> 7);
    int cl  = tid & 127;
    const float4* A4 = (const float4*)(ws + OO);    // [384][128]
    const float4* WT = (const float4*)(ws + WTO);   // [128][512]

    float acc[4];
    #pragma unroll
    for (int r = 0; r < 4; r++) acc[r] = 0.f;

    int k4b = kc * 16;
    #pragma unroll 8
    for (int i = 0; i < 16; i++) {
        int k4 = k4b + i;
        float4 w = WT[(size_t)k4 * 512 + c0 + cl];  // coalesced (1KB/wave)
        #pragma unroll
        for (int r = 0; r < 4; r++) {
            float4 a = A4[(r0 + r) * 128 + k4];     // wave-uniform -> s_load
            acc[r] += a.x * w.x + a.y * w.y + a.z * w.z + a.w * w.w;
        }
    }
    #pragma unroll
    for (int r = 0; r < 4; r++) pl[kc * 512 + r * 128 + cl] = acc[r];
    __syncthreads();
    if (tid < 512) {
        int r = tid >> 7, c2 = tid & 127;      // 512 outputs
        float v = 0.f;
        #pragma unroll
        for (int k = 0; k < 8; k++) v += pl[k * 512 + r * 128 + c2];
        out[(size_t)(r0 + r) * 512 + c0 + c2] = v + bo[c0 + c2];
    }
}

extern "C" void kernel_launch(void* const* d_in, const int* in_sizes, int n_in,
                              void* d_out, int out_size, void* d_ws, size_t ws_size,
                              hipStream_t stream) {
    const float* query  = (const float*)d_in[0];
    const float* entity = (const float*)d_in[1];
    // d_in[2] ex_entity, d_in[3] ex_relation: dead
    const float* Wq = (const float*)d_in[4];  const float* bq = (const float*)d_in[5];
    const float* Wk = (const float*)d_in[6];  const float* bk = (const float*)d_in[7];
    const float* Wv = (const float*)d_in[8];  const float* bv = (const float*)d_in[9];
    const float* We = (const float*)d_in[10]; const float* be = (const float*)d_in[11];
    // d_in[12..15] dead
    const float* Wa = (const float*)d_in[16]; const float* ba = (const float*)d_in[17];
    const float* Wo = (const float*)d_in[18]; const float* bo = (const float*)d_in[19];
    float* ws  = (float*)d_ws;
    float* out = (float*)d_out;

    hipLaunchKernelGGL(k_projprep, dim3(268), dim3(1024), 0, stream,
                       query, entity, Wq, bq, Wk, bk, Wv, bv, We, be, Wa, Wo, ws);
    hipLaunchKernelGGL(k_attn, dim3(384), dim3(1024), 0, stream, ba, ws);
    hipLaunchKernelGGL(k_out,  dim3(384), dim3(1024), 0, stream, bo, ws, out);
}